// Round 1
// baseline (338.734 us; speedup 1.0000x reference)
//
#include <hip/hip_runtime.h>

// EquivariantLayer on MI355X.
// Shapes: f[16][8][64][64], kernel[1][8][16][64][64] -> out[16][128][128][128]
// Pipeline:
//   1. rfft2_64 (f)          -> F  [16][8][64][33] cplx   (ws)
//   2. rfft2_64 (sym kernel) -> K  [8][16][64][33] cplx   (ws)
//   3. conv_mul              -> CV [16][16][64][33] cplx  (ws)
//   4. irfft_uv: per (b,j): upsample*TO_U/TO_V + irfft2@128 -> u,v stored in
//      d_out channels 64+j (u) and 96+j (v) of batch b     (reuse d_out as scratch)
//   5. irfft_fr: per (b,c): upsample + irfft2@128 -> out channels 0..7
//   6. cross: stage u,v chunk in LDS, write channels 8..127
//
// irfft2@128 with spectral support kx in [-31,31], ky in [0,31]:
//   step A (x-inverse): G[x,ky] = sum_ks C[ks,ky] e^{+2pi i k x/128}
//     parity: G[x0+64] = even-k sum - odd-k sum  (2x fewer MACs)
//   step B (y-inverse, real): out[x,y] = Re( sum_ky G[x,ky] e^{+2pi i ky y/128} )
//     with Hermitian 2x, upsample 2x and 1/16384 folded into C; same parity in ky.

#define PI_D 3.14159265358979323846

// ---------------- forward rfft2 of one 64x64 image per block ----------------
__global__ __launch_bounds__(256) void rfft2_64_kernel(const float* __restrict__ src,
                                                       float* __restrict__ dst,
                                                       int sym) {
  __shared__ float s_img[64][64];
  __shared__ float s_fre[64][33];
  __shared__ float s_fim[64][33];
  __shared__ float s_twc[64];
  __shared__ float s_tws[64];
  const int bid = blockIdx.x;
  const int tid = threadIdx.x;
  const float* img = src + (size_t)bid * 4096;

  if (tid < 64) {
    double a = -2.0 * PI_D * (double)tid / 64.0;  // forward sign
    s_twc[tid] = (float)cos(a);
    s_tws[tid] = (float)sin(a);
  }
  for (int idx = tid; idx < 4096; idx += 256) {
    int i = idx >> 6, j = idx & 63;
    float v;
    if (sym) {
      int ni = (64 - i) & 63, nj = (64 - j) & 63;
      v = (img[i * 64 + j] + img[nj * 64 + i] + img[ni * 64 + nj] + img[j * 64 + ni] +
           img[j * 64 + i] + img[i * 64 + nj] + img[nj * 64 + ni] + img[ni * 64 + j]) *
          0.125f;
    } else {
      v = img[idx];
    }
    s_img[i][j] = v;
  }
  __syncthreads();
  // row FFT along y (real -> 33 cplx)
  for (int o = tid; o < 64 * 33; o += 256) {
    int x = o / 33, ky = o - x * 33;
    float re = 0.f, im = 0.f;
#pragma unroll 8
    for (int y = 0; y < 64; ++y) {
      int t = (ky * y) & 63;
      float v = s_img[x][y];
      re += v * s_twc[t];
      im += v * s_tws[t];
    }
    s_fre[x][ky] = re;
    s_fim[x][ky] = im;
  }
  __syncthreads();
  // col FFT along x (cplx, full 64)
  float2* out = (float2*)(dst + (size_t)bid * 64 * 33 * 2);
  for (int o = tid; o < 64 * 33; o += 256) {
    int kx = o / 33, ky = o - kx * 33;
    float re = 0.f, im = 0.f;
#pragma unroll 8
    for (int x = 0; x < 64; ++x) {
      int t = (kx * x) & 63;
      float fr = s_fre[x][ky], fi = s_fim[x][ky];
      float c = s_twc[t], s = s_tws[t];
      re += fr * c - fi * s;
      im += fr * s + fi * c;
    }
    out[o] = make_float2(re, im);
  }
}

// ---------------- channel mixing: conv[b,j] = sum_i F[b,i]*K[i,j] ----------------
__global__ __launch_bounds__(256) void conv_mul_kernel(const float* __restrict__ Fv,
                                                       const float* __restrict__ Kv,
                                                       float* __restrict__ CVv) {
  int idx = blockIdx.x * 256 + threadIdx.x;  // over 16*16*2112
  if (idx >= 16 * 16 * 2112) return;
  int xy = idx % 2112;
  int t = idx / 2112;
  int j = t & 15, b = t >> 4;
  const float2* F2 = (const float2*)Fv;
  const float2* K2 = (const float2*)Kv;
  float re = 0.f, im = 0.f;
#pragma unroll
  for (int i = 0; i < 8; ++i) {
    float2 fv = F2[(b * 8 + i) * 2112 + xy];
    float2 kv = K2[(i * 16 + j) * 2112 + xy];
    re += fv.x * kv.x - fv.y * kv.y;
    im += fv.x * kv.y + fv.y * kv.x;
  }
  ((float2*)CVv)[idx] = make_float2(re, im);
}

// ---------------- irfft2@128 for u and v (one (b,j) per block) ----------------
__global__ __launch_bounds__(512) void irfft_uv_kernel(const float* __restrict__ CVv,
                                                       float* __restrict__ out) {
  __shared__ float s_c[64][33][2];
  __shared__ float s_g[128][32][2];
  __shared__ float s_twc[128];
  __shared__ float s_tws[128];
  const int bid = blockIdx.x;  // b*16 + j
  const int b = bid >> 4, j = bid & 15;
  const int tid = threadIdx.x;
  const float2* src = (const float2*)(CVv + (size_t)bid * 2112 * 2);

  if (tid < 128) {
    double a = 2.0 * PI_D * (double)tid / 128.0;  // inverse sign
    s_twc[tid] = (float)cos(a);
    s_tws[tid] = (float)sin(a);
  }
  for (int phase = 0; phase < 2; ++phase) {
    __syncthreads();
    // build C = conv * TO_{U,V} * scale  (W = i*conv pattern)
    for (int o = tid; o < 2112; o += 512) {
      int ks = o / 33;
      int ky = o - ks * 33;
      float2 cv = src[o];
      float re = cv.x, im = cv.y;
      int kx = (ks <= 32) ? ks : ks - 64;
      float fac;
      if (kx == 0 && ky == 0) {
        fac = 0.0f;
      } else {
        float invden = 1.0f / (float)(kx * kx + ky * ky);
        fac = (phase == 0) ? ((float)ky * invden) : (-(float)kx * invden);
      }
      float scale = (ky == 0) ? (2.0f / 16384.0f) : (4.0f / 16384.0f);
      if (ks == 32 || ky == 32) { re = 0.0f; im = 0.0f; }
      fac *= scale;
      s_c[ks][ky][0] = -im * fac;  // (re,im) * i*fac
      s_c[ks][ky][1] = re * fac;
    }
    __syncthreads();
    // step A: x-inverse with +-64 parity
    for (int o = tid; o < 2048; o += 512) {
      int x0 = o >> 5, ky = o & 31;
      float er = 0.f, ei = 0.f, odr = 0.f, odi = 0.f;
#pragma unroll 4
      for (int ks = 0; ks < 64; ++ks) {
        int kk = (ks <= 32) ? ks : (ks + 64);  // k mod 128
        int t = (kk * x0) & 127;
        float cr = s_c[ks][ky][0], ci = s_c[ks][ky][1];
        float c = s_twc[t], s = s_tws[t];
        float pr = cr * c - ci * s;
        float pi = cr * s + ci * c;
        if (ks & 1) { odr += pr; odi += pi; } else { er += pr; ei += pi; }
      }
      s_g[x0][ky][0] = er + odr;
      s_g[x0][ky][1] = ei + odi;
      s_g[x0 + 64][ky][0] = er - odr;
      s_g[x0 + 64][ky][1] = ei - odi;
    }
    __syncthreads();
    // step B: y-inverse (real) with +-64 parity; u -> ch 64+j, v -> ch 96+j
    float* dst = out + ((size_t)b * 128 + ((phase == 0) ? 64 : 96) + j) * 16384;
    for (int o = tid; o < 8192; o += 512) {
      int x = o >> 6, y0 = o & 63;
      float se = 0.f, so = 0.f;
#pragma unroll 8
      for (int ky = 0; ky < 32; ++ky) {
        int t = (ky * y0) & 127;
        float v = s_g[x][ky][0] * s_twc[t] - s_g[x][ky][1] * s_tws[t];
        if (ky & 1) so += v; else se += v;
      }
      dst[x * 128 + y0] = se + so;
      dst[x * 128 + y0 + 64] = se - so;
    }
  }
}

// ---------------- irfft2@128 for fr (one (b,c) per block) ----------------
__global__ __launch_bounds__(256) void irfft_fr_kernel(const float* __restrict__ Fv,
                                                       float* __restrict__ out) {
  __shared__ float s_c[64][33][2];
  __shared__ float s_g[128][32][2];
  __shared__ float s_twc[128];
  __shared__ float s_tws[128];
  const int bid = blockIdx.x;  // b*8 + c
  const int b = bid >> 3, c = bid & 7;
  const int tid = threadIdx.x;
  const float2* src = (const float2*)(Fv + (size_t)bid * 2112 * 2);

  if (tid < 128) {
    double a = 2.0 * PI_D * (double)tid / 128.0;
    s_twc[tid] = (float)cos(a);
    s_tws[tid] = (float)sin(a);
  }
  for (int o = tid; o < 2112; o += 256) {
    int ks = o / 33;
    int ky = o - ks * 33;
    float2 cv = src[o];
    float re = cv.x, im = cv.y;
    float scale = (ky == 0) ? (2.0f / 16384.0f) : (4.0f / 16384.0f);
    if (ks == 32 || ky == 32) { re = 0.0f; im = 0.0f; }
    s_c[ks][ky][0] = re * scale;
    s_c[ks][ky][1] = im * scale;
  }
  __syncthreads();
  for (int o = tid; o < 2048; o += 256) {
    int x0 = o >> 5, ky = o & 31;
    float er = 0.f, ei = 0.f, odr = 0.f, odi = 0.f;
#pragma unroll 4
    for (int ks = 0; ks < 64; ++ks) {
      int kk = (ks <= 32) ? ks : (ks + 64);
      int t = (kk * x0) & 127;
      float cr = s_c[ks][ky][0], ci = s_c[ks][ky][1];
      float c = s_twc[t], s = s_tws[t];
      float pr = cr * c - ci * s;
      float pi = cr * s + ci * c;
      if (ks & 1) { odr += pr; odi += pi; } else { er += pr; ei += pi; }
    }
    s_g[x0][ky][0] = er + odr;
    s_g[x0][ky][1] = ei + odi;
    s_g[x0 + 64][ky][0] = er - odr;
    s_g[x0 + 64][ky][1] = ei - odi;
  }
  __syncthreads();
  float* dst = out + ((size_t)b * 128 + c) * 16384;
  for (int o = tid; o < 8192; o += 256) {
    int x = o >> 6, y0 = o & 63;
    float se = 0.f, so = 0.f;
#pragma unroll 8
    for (int ky = 0; ky < 32; ++ky) {
      int t = (ky * y0) & 127;
      float v = s_g[x][ky][0] * s_twc[t] - s_g[x][ky][1] * s_tws[t];
      if (ky & 1) so += v; else se += v;
    }
    dst[x * 128 + y0] = se + so;
    dst[x * 128 + y0 + 64] = se - so;
  }
}

// ---------------- cross products: out[8+p] = u[i]v[j]-u[j]v[i] ----------------
__global__ __launch_bounds__(256) void cross_kernel(float* __restrict__ out) {
  __shared__ float s_u[16][512];
  __shared__ float s_v[16][512];
  const int b = blockIdx.x >> 5;      // 32 chunks of 512 points
  const int chunk = blockIdx.x & 31;
  const int tid = threadIdx.x;
  const int base = chunk * 512;
  for (int idx = tid; idx < 16 * 512; idx += 256) {
    int ch = idx >> 9, o = idx & 511;
    s_u[ch][o] = out[((size_t)b * 128 + 64 + ch) * 16384 + base + o];
    s_v[ch][o] = out[((size_t)b * 128 + 96 + ch) * 16384 + base + o];
  }
  __syncthreads();
  int i = 0, j = 1;
  for (int p = 0; p < 120; ++p) {
    float* dst = out + ((size_t)b * 128 + 8 + p) * 16384 + base;
    for (int o = tid; o < 512; o += 256) {
      dst[o] = s_u[i][o] * s_v[j][o] - s_u[j][o] * s_v[i][o];
    }
    ++j;
    if (j == 16) { ++i; j = i + 1; }
  }
}

extern "C" void kernel_launch(void* const* d_in, const int* in_sizes, int n_in,
                              void* d_out, int out_size, void* d_ws, size_t ws_size,
                              hipStream_t stream) {
  const float* f = (const float*)d_in[0];     // [16][8][64][64]
  const float* kern = (const float*)d_in[1];  // [1][8][16][64][64]
  float* out = (float*)d_out;                 // [16][128][128][128]
  float* ws = (float*)d_ws;

  float* Fv = ws;                  // 16*8*64*33*2  = 540672 floats
  float* Kv = ws + 540672;         // 8*16*64*33*2  = 540672
  float* CVv = ws + 1081344;       // 16*16*64*33*2 = 1081344  (total 8.65 MB)

  rfft2_64_kernel<<<128, 256, 0, stream>>>(f, Fv, 0);
  rfft2_64_kernel<<<128, 256, 0, stream>>>(kern, Kv, 1);
  conv_mul_kernel<<<2112, 256, 0, stream>>>(Fv, Kv, CVv);
  irfft_uv_kernel<<<256, 512, 0, stream>>>(CVv, out);
  irfft_fr_kernel<<<128, 256, 0, stream>>>(Fv, out);
  cross_kernel<<<512, 256, 0, stream>>>(out);
}